// Round 5
// baseline (7154.884 us; speedup 1.0000x reference)
//
#include <hip/hip_runtime.h>
#include <cstdint>
#include <cstddef>

// Problem dims
#define NB 16
#define NT 1024
#define NE 1024
#define NS 256
#define ND 512
#define NH 128
#define T0 16

// ---- workspace layout (float offsets) ----
#define OFF_US   ((size_t)0)
#define OFF_HU   ((size_t)4194304)
#define OFF_U3   ((size_t)8388608)
#define OFF_KT   ((size_t)12582912)
#define OFF_HT   ((size_t)12845056)
#define OFF_AT   ((size_t)12976128)
#define OFF_G    ((size_t)13041664)
#define OFF_IG   ((size_t)13107200)
#define OFF_MINF ((size_t)13172736)
#define OFF_WZT  ((size_t)13238272)
#define OFF_WRT  ((size_t)13287424)
#define OFF_WHT  ((size_t)13336576)
#define OFF_PACK ((size_t)13385728)

// pack sub-offsets (shorts)
#define PK_A 0
#define PK_G 65536
#define PK_M 131072
#define PK_Z 196608
#define PK_R 245760
#define PK_H 294912
#define PK_O 344064

typedef short bf16x8 __attribute__((ext_vector_type(8)));
typedef float f32x4 __attribute__((ext_vector_type(4)));
typedef unsigned int u32x2 __attribute__((ext_vector_type(2)));

#define MFMA(a, b, c) __builtin_amdgcn_mfma_f32_16x16x32_bf16((a), (b), (c), 0, 0, 0)

// barrier WITHOUT vmcnt drain: LDS handoff only; global loads stay in flight.
#define SYNCW() do { \
    __builtin_amdgcn_sched_barrier(0); \
    asm volatile("s_waitcnt lgkmcnt(0)" ::: "memory"); \
    __builtin_amdgcn_s_barrier(); \
    __builtin_amdgcn_sched_barrier(0); \
} while (0)

__device__ __forceinline__ float gelu_tanh(float v) {
    const float c = 0.7978845608028654f;
    float t = tanhf(c * (v + 0.044715f * v * v * v));
    return 0.5f * v * (1.0f + t);
}
__device__ __forceinline__ float softplus_f(float x) {
    if (x > 20.0f) return x;
    return log1pf(expf(x));
}
__device__ __forceinline__ short f2bf_s(float f) {
    unsigned u = __float_as_uint(f);
    u += 0x7fffu + ((u >> 16) & 1u);
    return (short)(u >> 16);
}
__device__ __forceinline__ unsigned pk_bf(float a, float b) {
    return ((unsigned)(unsigned short)f2bf_s(b) << 16) | (unsigned)(unsigned short)f2bf_s(a);
}

// 4x4 transpose among lane quads (lanes l, l^1, l^2, l^3). qi = lane&3.
// in: v[j] = val(row base+j, col of this lane); out: v[j] = val(row base+qi, col quadbase+j)
__device__ __forceinline__ void tr4(f32x4& v, int qi) {
    bool s1 = qi & 1;
    float a = s1 ? v[0] : v[1];
    float b = s1 ? v[2] : v[3];
    a = __shfl_xor(a, 1, 64);
    b = __shfl_xor(b, 1, 64);
    if (s1) { v[0] = a; v[2] = b; } else { v[1] = a; v[3] = b; }
    bool s2 = qi & 2;
    float c = s2 ? v[0] : v[2];
    float d = s2 ? v[1] : v[3];
    c = __shfl_xor(c, 2, 64);
    d = __shfl_xor(d, 2, 64);
    if (s2) { v[0] = c; v[1] = d; } else { v[2] = c; v[3] = d; }
}

__device__ __forceinline__ void st_bf8(char* base, int stride, int row, int byteoff,
                                       const f32x4& v) {
    u32x2 p;
    p[0] = pk_bf(v[0], v[1]);
    p[1] = pk_bf(v[2], v[3]);
    *(u32x2*)(base + row * stride + byteoff) = p;
}

// A-fragment read: lane (lr,lg) reads row lr, k-cols kk*32 + lg*8 .. +7 (bf16)
#define FRAG(buf, stride, kk) (*(const bf16x8*)((buf) + lr * (stride) + (kk) * 64 + lg * 16))

// ---- P/K covariance recurrence (data-independent) ----
__global__ __launch_bounds__(512) void k_precompute(const float* __restrict__ Q,
                                                    const float* __restrict__ R,
                                                    float* __restrict__ Kt) {
    __shared__ float red[512];
    __shared__ float r_eff_sh;
    const int t = threadIdx.x;
    red[t] = softplus_f(R[t]);
    __syncthreads();
    for (int s = 256; s > 0; s >>= 1) {
        if (t < s) red[t] += red[t + s];
        __syncthreads();
    }
    if (t == 0) r_eff_sh = red[0] / 512.0f;
    __syncthreads();
    const float r_eff = r_eff_sh;
    if (t < NS) {
        const float q = softplus_f(Q[t]);
        float P = 1.0f;
        for (int step = 0; step < NT; ++step) {
            float Pp = fminf(fmaxf(P + q, 1e-6f), 10.0f);
            float K  = fminf(fmaxf(Pp / (Pp + r_eff + 1e-6f), 0.0f), 1.0f);
            Kt[(size_t)step * NS + t] = K;
            P = fminf(fmaxf(Pp * (1.0f - K), 1e-6f), 10.0f);
        }
    }
}

// ---- generic transpose ----
__global__ void k_transpose(const float* __restrict__ in, float* __restrict__ outp,
                            int Rr, int Cc) {
    int i = blockIdx.x * 256 + threadIdx.x;
    if (i < Rr * Cc) {
        int r = i / Cc, c = i % Cc;
        outp[(size_t)c * Rr + r] = in[i];
    }
}

// ---- IG = I - G*diag(Kinf) ----
__global__ void k_ig(const float* __restrict__ G, const float* __restrict__ Kt,
                     float* __restrict__ IG) {
    int i = blockIdx.x * 256 + threadIdx.x;
    if (i >= NS * NS) return;
    int r = i >> 8, c = i & 255;
    float kinf = Kt[(size_t)(NT - 1) * NS + c];
    IG[i] = ((r == c) ? 1.0f : 0.0f) - G[i] * kinf;
}

// ---- ustate3[t][m][s] = us + K_t*(Hu - usG) ----
__global__ void k_fuse(const float* __restrict__ us, const float* __restrict__ usG,
                       const float* __restrict__ Hu, const float* __restrict__ Kt,
                       float* __restrict__ u3) {
    int i = blockIdx.x * 256 + threadIdx.x;
    if (i >= NT * NB * NS) return;
    int s = i & 255;
    int tm = i >> 8;
    int m = tm & 15, t = tm >> 4;
    size_t src = ((size_t)m * NT + t) * NS + s;
    float k = Kt[(size_t)t * NS + s];
    u3[i] = us[src] + k * (Hu[src] - usG[src]);
}

// ---- pack W[K][N] f32 -> bf16 B-operand fragments ----
__global__ void k_pack(const float* __restrict__ W, short* __restrict__ dst, int K, int N) {
    int f = blockIdx.x * 256 + threadIdx.x;
    if (f >= K * N) return;
    const int j = f & 7, l = (f >> 3) & 63, tile = f >> 9;
    const int KS = K >> 5;
    const int nt = tile / KS, ks = tile - nt * KS;
    const int k = ks * 32 + (l >> 4) * 8 + j;
    const int n = nt * 16 + (l & 15);
    dst[f] = f2bf_s(W[(size_t)k * N + n]);
}

// ---- f32 tiled GEMM ----
__global__ __launch_bounds__(256) void k_gemm(const float* __restrict__ Am,
                                              const float* __restrict__ Bm,
                                              const float* __restrict__ bias,
                                              const float* __restrict__ resid,
                                              float* __restrict__ Cm,
                                              int M, int N, int K, int act) {
    __shared__ __align__(16) float As[16][68];
    __shared__ __align__(16) float Bs[16][68];
    const int tid = threadIdx.x;
    const int bn = blockIdx.x, bm = blockIdx.y;
    const int row0 = bm * 64, col0 = bn * 64;
    const int tx = tid & 15, ty = tid >> 4;
    const int ar = tid >> 2, ac = (tid & 3) << 2;
    const int bk = tid >> 4, bc = (tid & 15) << 2;

    float acc[4][4];
#pragma unroll
    for (int i = 0; i < 4; ++i)
#pragma unroll
        for (int j = 0; j < 4; ++j) acc[i][j] = 0.0f;

    for (int k0 = 0; k0 < K; k0 += 16) {
        float4 av = *(const float4*)(Am + (size_t)(row0 + ar) * K + k0 + ac);
        float4 bv = *(const float4*)(Bm + (size_t)(k0 + bk) * N + col0 + bc);
        As[ac + 0][ar] = av.x; As[ac + 1][ar] = av.y;
        As[ac + 2][ar] = av.z; As[ac + 3][ar] = av.w;
        *(float4*)&Bs[bk][bc] = bv;
        __syncthreads();
#pragma unroll
        for (int kk = 0; kk < 16; ++kk) {
            const float a0 = As[kk][ty * 4 + 0], a1 = As[kk][ty * 4 + 1];
            const float a2 = As[kk][ty * 4 + 2], a3 = As[kk][ty * 4 + 3];
            const float4 b4 = *(const float4*)&Bs[kk][tx * 4];
            acc[0][0] += a0 * b4.x; acc[0][1] += a0 * b4.y; acc[0][2] += a0 * b4.z; acc[0][3] += a0 * b4.w;
            acc[1][0] += a1 * b4.x; acc[1][1] += a1 * b4.y; acc[1][2] += a1 * b4.z; acc[1][3] += a1 * b4.w;
            acc[2][0] += a2 * b4.x; acc[2][1] += a2 * b4.y; acc[2][2] += a2 * b4.z; acc[2][3] += a2 * b4.w;
            acc[3][0] += a3 * b4.x; acc[3][1] += a3 * b4.y; acc[3][2] += a3 * b4.z; acc[3][3] += a3 * b4.w;
        }
        __syncthreads();
    }
#pragma unroll
    for (int i = 0; i < 4; ++i) {
        const int r = row0 + ty * 4 + i;
#pragma unroll
        for (int j = 0; j < 4; ++j) {
            const int c = col0 + tx * 4 + j;
            float v = acc[i][j];
            if (bias) v += bias[c];
            if (act) v = gelu_tanh(v);
            if (resid) v += resid[(size_t)r * N + c];
            Cm[(size_t)r * N + c] = v;
        }
    }
}

// =====================================================================
// MFMA scan. 8 waves. Resident: M_inf(64) + Wz(48) + Wr(48) + Wout(32)
// = 192 regs/lane (VGPR+AGPR). Wh in LDS. Odd-16B strides (NO xor —
// stride rotation alone de-conflicts). All LDS stores are b64 after
// in-wave 4x4 shfl transpose. Custom barriers (no vmcnt drain) +
// register-pipelined u3 prefetch.
// =====================================================================
#define XA_STR 528   // 256 bf16 cols + pad, 33*16B
#define HX_STR 784   // [h(128) | x_post(256)] + pad, 49*16B
#define RG_STR 272   // 128 bf16 cols + pad, 17*16B

__device__ __forceinline__ void gru_phases(
    int t, int w, int l, int lr, int lg, int qi, int q, int row,
    f32x4& za, f32x4& ra, const f32x4& xqt0, const f32x4& xqt1,
    float (&hFr)[4], float bzv, float brv, float bhv,
    const bf16x8 (&rZ)[12], const bf16x8 (&rR)[12], const bf16x8 (&rO)[2][4],
    const short* WH, char* XA, char* HX, char* RGs, float* __restrict__ xs)
{
    const int c0 = 32 * w;
    // ---- PH2: gates x-part + Wh.x part ----
    f32x4 ha = {0.f, 0.f, 0.f, 0.f};
#pragma unroll
    for (int kk = 4; kk < 12; ++kk) {
        bf16x8 ax = FRAG(HX, HX_STR, kk);
        bf16x8 bh_ = *(const bf16x8*)(WH + ((size_t)(w * 12 + kk) * 64 + l) * 8);
        za = MFMA(ax, rZ[kk], za);
        ra = MFMA(ax, rR[kk], ra);
        ha = MFMA(ax, bh_, ha);
    }
    f32x4 zf, rg;
#pragma unroll
    for (int r = 0; r < 4; ++r) {
        zf[r] = 1.0f / (1.0f + expf(-(za[r] + bzv)));
        float rv = 1.0f / (1.0f + expf(-(ra[r] + brv)));
        rg[r] = rv * hFr[r];
    }
    tr4(rg, qi);
    st_bf8(RGs, RG_STR, row, (16 * w + 4 * q) * 2, rg);
    SYNCW();  // bar_B
    // ---- PH3: ha += Wh.rg part; h update ----
#pragma unroll
    for (int kk = 0; kk < 4; ++kk) {
        bf16x8 ar_ = FRAG(RGs, RG_STR, kk);
        bf16x8 bh_ = *(const bf16x8*)(WH + ((size_t)(w * 12 + kk) * 64 + l) * 8);
        ha = MFMA(ar_, bh_, ha);
    }
    f32x4 hn;
#pragma unroll
    for (int r = 0; r < 4; ++r) {
        float hc = tanhf(ha[r] + bhv);
        hn[r] = (1.0f - zf[r]) * hFr[r] + zf[r] * hc;
        hFr[r] = hn[r];
    }
    tr4(hn, qi);
    st_bf8(HX, HX_STR, row, (16 * w + 4 * q) * 2, hn);
    SYNCW();  // bar_C
    // ---- PH4: x_final = x_post + h_new @ W_out ----
    f32x4 o0 = {0.f, 0.f, 0.f, 0.f}, o1 = {0.f, 0.f, 0.f, 0.f};
#pragma unroll
    for (int kk = 0; kk < 4; ++kk) {
        bf16x8 ah = FRAG(HX, HX_STR, kk);
        o0 = MFMA(ah, rO[0][kk], o0);
        o1 = MFMA(ah, rO[1][kk], o1);
    }
    tr4(o0, qi);
    tr4(o1, qi);
    f32x4 xf0 = xqt0 + o0;
    f32x4 xf1 = xqt1 + o1;
    st_bf8(XA, XA_STR, row, (c0 + 4 * q) * 2, xf0);
    st_bf8(XA, XA_STR, row, (c0 + 16 + 4 * q) * 2, xf1);
    *(f32x4*)(xs + ((size_t)row * NT + t) * NS + c0 + 4 * q) = xf0;
    *(f32x4*)(xs + ((size_t)row * NT + t) * NS + c0 + 16 + 4 * q) = xf1;
    SYNCW();  // bar_D
}

__global__ __launch_bounds__(512, 2) void k_scan_mfma(
    const short* __restrict__ pM, const short* __restrict__ pA, const short* __restrict__ pG,
    const short* __restrict__ pZ, const short* __restrict__ pR, const short* __restrict__ pHg,
    const short* __restrict__ pO,
    const float* __restrict__ bz, const float* __restrict__ br, const float* __restrict__ bh,
    const float* __restrict__ us, const float* __restrict__ Hu, const float* __restrict__ u3,
    const float* __restrict__ Kt, float* __restrict__ xs)
{
    __shared__ __align__(16) char XA[16 * XA_STR];
    __shared__ __align__(16) char HX[16 * HX_STR];
    __shared__ __align__(16) char RGs[16 * RG_STR];
    __shared__ __align__(16) short WH[384 * 128];

    const int tid = threadIdx.x, w = tid >> 6, l = tid & 63;
    const int lr = l & 15, lg = l >> 4;
    const int qi = lr & 3, q = lr >> 2;
    const int row = 4 * lg + qi;
    const int c0 = 32 * w;
    const int colg = 16 * w + lr;

    // stage Wh into LDS (96 KB)
    for (int i = tid; i < 6144; i += 512) ((int4*)WH)[i] = ((const int4*)pHg)[i];
    for (int i = tid; i < 16 * XA_STR / 4; i += 512) ((int*)XA)[i] = 0;
    for (int i = tid; i < 16 * HX_STR / 4; i += 512) ((int*)HX)[i] = 0;

    const float bzv = bz[colg], brv = br[colg], bhv = bh[colg];
    float hFr[4] = {0.f, 0.f, 0.f, 0.f};

    // resident GRU weights
    bf16x8 rZ[12], rR[12], rO[2][4];
#pragma unroll
    for (int ks = 0; ks < 12; ++ks) {
        rZ[ks] = *(const bf16x8*)(pZ + ((size_t)(w * 12 + ks) * 64 + l) * 8);
        rR[ks] = *(const bf16x8*)(pR + ((size_t)(w * 12 + ks) * 64 + l) * 8);
    }
#pragma unroll
    for (int nt = 0; nt < 2; ++nt)
#pragma unroll
        for (int ks = 0; ks < 4; ++ks)
            rO[nt][ks] = *(const bf16x8*)(pO + ((size_t)((2 * w + nt) * 4 + ks) * 64 + l) * 8);

    __syncthreads();

    // ---------------- early phase: exact per-t K ----------------
    for (int t = 0; t < T0; ++t) {
        // loads first (hidden under MFMAs)
        f32x4 us0, us1, hu0, hu1;
#pragma unroll
        for (int r = 0; r < 4; ++r) {
            const int m = lg * 4 + r;
            size_t o = ((size_t)m * NT + t) * NS;
            us0[r] = us[o + c0 + lr];      us1[r] = us[o + c0 + 16 + lr];
            hu0[r] = Hu[o + c0 + lr];      hu1[r] = Hu[o + c0 + 16 + lr];
        }
        const float kv0 = Kt[(size_t)t * NS + c0 + lr];
        const float kv1 = Kt[(size_t)t * NS + c0 + 16 + lr];
        // E1: x_pred = x_est@A^T (streamed) + us ; gates-h partial
        f32x4 p0 = {0.f, 0.f, 0.f, 0.f}, p1 = {0.f, 0.f, 0.f, 0.f};
#pragma unroll 2
        for (int ks = 0; ks < 8; ++ks) {
            bf16x8 a = FRAG(XA, XA_STR, ks);
            bf16x8 b0 = *(const bf16x8*)(pA + ((size_t)((2 * w + 0) * 8 + ks) * 64 + l) * 8);
            bf16x8 b1 = *(const bf16x8*)(pA + ((size_t)((2 * w + 1) * 8 + ks) * 64 + l) * 8);
            p0 = MFMA(a, b0, p0);
            p1 = MFMA(a, b1, p1);
        }
        f32x4 za = {0.f, 0.f, 0.f, 0.f}, ra = {0.f, 0.f, 0.f, 0.f};
#pragma unroll
        for (int kk = 0; kk < 4; ++kk) {
            bf16x8 ah = FRAG(HX, HX_STR, kk);
            za = MFMA(ah, rZ[kk], za);
            ra = MFMA(ah, rR[kk], ra);
        }
        p0 += us0;
        p1 += us1;
        {
            f32x4 pt0 = p0, pt1 = p1;
            tr4(pt0, qi);
            tr4(pt1, qi);
            st_bf8(HX, HX_STR, row, 256 + (c0 + 4 * q) * 2, pt0);
            st_bf8(HX, HX_STR, row, 256 + (c0 + 16 + 4 * q) * 2, pt1);
        }
        SYNCW();
        // E2a: g = x_pred @ G (streamed)
        f32x4 g0 = {0.f, 0.f, 0.f, 0.f}, g1 = {0.f, 0.f, 0.f, 0.f};
#pragma unroll 2
        for (int ks = 0; ks < 8; ++ks) {
            bf16x8 ax = FRAG(HX, HX_STR, 4 + ks);
            bf16x8 b0 = *(const bf16x8*)(pG + ((size_t)((2 * w + 0) * 8 + ks) * 64 + l) * 8);
            bf16x8 b1 = *(const bf16x8*)(pG + ((size_t)((2 * w + 1) * 8 + ks) * 64 + l) * 8);
            g0 = MFMA(ax, b0, g0);
            g1 = MFMA(ax, b1, g1);
        }
        SYNCW();  // all reads of x_pred done before overwrite
        // E2b: x_post = x_pred + K.*(Hu - g)
        f32x4 xq0, xq1;
#pragma unroll
        for (int r = 0; r < 4; ++r) {
            xq0[r] = p0[r] + kv0 * (hu0[r] - g0[r]);
            xq1[r] = p1[r] + kv1 * (hu1[r] - g1[r]);
        }
        tr4(xq0, qi);
        tr4(xq1, qi);
        st_bf8(HX, HX_STR, row, 256 + (c0 + 4 * q) * 2, xq0);
        st_bf8(HX, HX_STR, row, 256 + (c0 + 16 + 4 * q) * 2, xq1);
        SYNCW();  // bar_A
        gru_phases(t, w, l, lr, lg, qi, q, row, za, ra, xq0, xq1, hFr,
                   bzv, brv, bhv, rZ, rR, rO, WH, XA, HX, RGs, xs);
    }

    // load fused Kalman matrix
    bf16x8 rM[2][8];
#pragma unroll
    for (int nt = 0; nt < 2; ++nt)
#pragma unroll
        for (int ks = 0; ks < 8; ++ks)
            rM[nt][ks] = *(const bf16x8*)(pM + ((size_t)((2 * w + nt) * 8 + ks) * 64 + l) * 8);

    // u3 pipeline prologue (TR layout: lane = row, 4 cols)
    f32x4 cu0 = *(const f32x4*)(u3 + (size_t)T0 * (NB * NS) + (size_t)row * NS + c0 + 4 * q);
    f32x4 cu1 = *(const f32x4*)(u3 + (size_t)T0 * (NB * NS) + (size_t)row * NS + c0 + 16 + 4 * q);

    // ---------------- main phase: fused one-matvec Kalman ----------------
    for (int t = T0; t < NT; ++t) {
        // prefetch next step's u3 (stays in flight across barriers)
        const int tn = (t + 1 < NT) ? (t + 1) : t;
        f32x4 nx0 = *(const f32x4*)(u3 + (size_t)tn * (NB * NS) + (size_t)row * NS + c0 + 4 * q);
        f32x4 nx1 = *(const f32x4*)(u3 + (size_t)tn * (NB * NS) + (size_t)row * NS + c0 + 16 + 4 * q);

        // PH1: x_post = x_est @ M_inf + u3_t ; gates-h partial
        f32x4 acc0 = {0.f, 0.f, 0.f, 0.f}, acc1 = {0.f, 0.f, 0.f, 0.f};
#pragma unroll
        for (int ks = 0; ks < 8; ++ks) {
            bf16x8 a = FRAG(XA, XA_STR, ks);
            acc0 = MFMA(a, rM[0][ks], acc0);
            acc1 = MFMA(a, rM[1][ks], acc1);
        }
        f32x4 za = {0.f, 0.f, 0.f, 0.f}, ra = {0.f, 0.f, 0.f, 0.f};
#pragma unroll
        for (int kk = 0; kk < 4; ++kk) {
            bf16x8 ah = FRAG(HX, HX_STR, kk);
            za = MFMA(ah, rZ[kk], za);
            ra = MFMA(ah, rR[kk], ra);
        }
        tr4(acc0, qi);
        tr4(acc1, qi);
        f32x4 xqt0 = acc0 + cu0;
        f32x4 xqt1 = acc1 + cu1;
        st_bf8(HX, HX_STR, row, 256 + (c0 + 4 * q) * 2, xqt0);
        st_bf8(HX, HX_STR, row, 256 + (c0 + 16 + 4 * q) * 2, xqt1);
        SYNCW();  // bar_A
        gru_phases(t, w, l, lr, lg, qi, q, row, za, ra, xqt0, xqt1, hFr,
                   bzv, brv, bhv, rZ, rR, rO, WH, XA, HX, RGs, xs);
        cu0 = nx0;
        cu1 = nx1;
    }
}

extern "C" void kernel_launch(void* const* d_in, const int* in_sizes, int n_in,
                              void* d_out, int out_size, void* d_ws, size_t ws_size,
                              hipStream_t stream) {
    (void)in_sizes; (void)n_in; (void)out_size; (void)ws_size;
    const float* x       = (const float*)d_in[0];
    const float* W_in    = (const float*)d_in[1];
    const float* b_in    = (const float*)d_in[2];
    const float* W_state = (const float*)d_in[3];
    const float* b_state = (const float*)d_in[4];
    const float* A       = (const float*)d_in[5];
    const float* H       = (const float*)d_in[6];
    const float* Q       = (const float*)d_in[7];
    const float* R       = (const float*)d_in[8];
    const float* W_z     = (const float*)d_in[9];
    const float* W_r     = (const float*)d_in[10];
    const float* W_h     = (const float*)d_in[11];
    const float* b_z     = (const float*)d_in[12];
    const float* b_r     = (const float*)d_in[13];
    const float* b_h     = (const float*)d_in[14];
    const float* W_out   = (const float*)d_in[15];
    const float* W_outp  = (const float*)d_in[16];
    const float* b_outp  = (const float*)d_in[17];
    float* out = (float*)d_out;
    float* w = (float*)d_ws;

    float* us   = w + OFF_US;
    float* Hu   = w + OFF_HU;
    float* u3   = w + OFF_U3;
    float* Kt   = w + OFF_KT;
    float* Ht   = w + OFF_HT;
    float* At   = w + OFF_AT;
    float* G    = w + OFF_G;
    float* IG   = w + OFF_IG;
    float* Minf = w + OFF_MINF;
    float* Wzt  = w + OFF_WZT;
    float* Wrt  = w + OFF_WRT;
    float* Wht  = w + OFF_WHT;
    short* pk   = (short*)(w + OFF_PACK);

    float* usG = out;                        // d_out lower half (scratch)
    float* u   = out + (size_t)8388608;      // d_out upper half
    float* xs  = out + (size_t)8388608;      // overwrites u (dead pre-scan)
    float* obs = w + OFF_US;                 // us+Hu region (dead after scan)

    const int M = NB * NT;  // 16384

    hipLaunchKernelGGL(k_precompute, dim3(1), dim3(512), 0, stream, Q, R, Kt);
    hipLaunchKernelGGL(k_transpose, dim3((NS * NS + 255) / 256), dim3(256), 0, stream, A, At, NS, NS);
    hipLaunchKernelGGL(k_transpose, dim3((ND * NS + 255) / 256), dim3(256), 0, stream, H, Ht, ND, NS);
    hipLaunchKernelGGL(k_transpose, dim3((NH * 384 + 255) / 256), dim3(256), 0, stream, W_z, Wzt, NH, 384);
    hipLaunchKernelGGL(k_transpose, dim3((NH * 384 + 255) / 256), dim3(256), 0, stream, W_r, Wrt, NH, 384);
    hipLaunchKernelGGL(k_transpose, dim3((NH * 384 + 255) / 256), dim3(256), 0, stream, W_h, Wht, NH, 384);
    // u = gelu(x @ W_in + b_in)
    hipLaunchKernelGGL(k_gemm, dim3(ND / 64, M / 64), dim3(256), 0, stream,
                       x, W_in, b_in, nullptr, u, M, ND, NE, 1);
    // us = u @ W_state + b_state
    hipLaunchKernelGGL(k_gemm, dim3(NS / 64, M / 64), dim3(256), 0, stream,
                       u, W_state, b_state, nullptr, us, M, NS, ND, 0);
    // Hu = u @ H
    hipLaunchKernelGGL(k_gemm, dim3(NS / 64, M / 64), dim3(256), 0, stream,
                       u, H, nullptr, nullptr, Hu, M, NS, ND, 0);
    // G = H^T @ H
    hipLaunchKernelGGL(k_gemm, dim3(NS / 64, NS / 64), dim3(256), 0, stream,
                       Ht, H, nullptr, nullptr, G, NS, NS, ND, 0);
    // usG = us @ G
    hipLaunchKernelGGL(k_gemm, dim3(NS / 64, M / 64), dim3(256), 0, stream,
                       us, G, nullptr, nullptr, usG, M, NS, NS, 0);
    // IG = I - G diag(Kinf); Minf = At @ IG
    hipLaunchKernelGGL(k_ig, dim3(256), dim3(256), 0, stream, G, Kt, IG);
    hipLaunchKernelGGL(k_gemm, dim3(NS / 64, NS / 64), dim3(256), 0, stream,
                       At, IG, nullptr, nullptr, Minf, NS, NS, NS, 0);
    // ustate3
    hipLaunchKernelGGL(k_fuse, dim3((NT * NB * NS) / 256), dim3(256), 0, stream,
                       us, usG, Hu, Kt, u3);
    // packs
    hipLaunchKernelGGL(k_pack, dim3((NS * NS + 255) / 256), dim3(256), 0, stream, At, pk + PK_A, NS, NS);
    hipLaunchKernelGGL(k_pack, dim3((NS * NS + 255) / 256), dim3(256), 0, stream, G, pk + PK_G, NS, NS);
    hipLaunchKernelGGL(k_pack, dim3((NS * NS + 255) / 256), dim3(256), 0, stream, Minf, pk + PK_M, NS, NS);
    hipLaunchKernelGGL(k_pack, dim3((384 * NH + 255) / 256), dim3(256), 0, stream, Wzt, pk + PK_Z, 384, NH);
    hipLaunchKernelGGL(k_pack, dim3((384 * NH + 255) / 256), dim3(256), 0, stream, Wrt, pk + PK_R, 384, NH);
    hipLaunchKernelGGL(k_pack, dim3((384 * NH + 255) / 256), dim3(256), 0, stream, Wht, pk + PK_H, 384, NH);
    hipLaunchKernelGGL(k_pack, dim3((NH * NS + 255) / 256), dim3(256), 0, stream, W_out, pk + PK_O, NH, NS);
    // scan
    hipLaunchKernelGGL(k_scan_mfma, dim3(1), dim3(512), 0, stream,
                       pk + PK_M, pk + PK_A, pk + PK_G, pk + PK_Z, pk + PK_R, pk + PK_H, pk + PK_O,
                       b_z, b_r, b_h, us, Hu, u3, Kt, xs);
    // obs = xs @ H^T
    hipLaunchKernelGGL(k_gemm, dim3(ND / 64, M / 64), dim3(256), 0, stream,
                       xs, Ht, nullptr, nullptr, obs, M, ND, NS, 0);
    // out = obs @ W_outp + b_outp + x
    hipLaunchKernelGGL(k_gemm, dim3(NE / 64, M / 64), dim3(256), 0, stream,
                       obs, W_outp, b_outp, x, out, M, NE, ND, 0);
}

// Round 8
// 4602.203 us; speedup vs baseline: 1.5547x; 1.5547x over previous
//
#include <hip/hip_runtime.h>
#include <cstdint>
#include <cstddef>

// Problem dims
#define NB 16
#define NT 1024
#define NE 1024
#define NS 256
#define ND 512
#define NH 128
#define T0 16

// ---- workspace layout (float offsets) ----
#define OFF_US   ((size_t)0)
#define OFF_HU   ((size_t)4194304)
#define OFF_U3   ((size_t)8388608)
#define OFF_KT   ((size_t)12582912)
#define OFF_HT   ((size_t)12845056)
#define OFF_AT   ((size_t)12976128)
#define OFF_G    ((size_t)13041664)
#define OFF_IG   ((size_t)13107200)
#define OFF_MINF ((size_t)13172736)
#define OFF_WZT  ((size_t)13238272)
#define OFF_WRT  ((size_t)13287424)
#define OFF_WHT  ((size_t)13336576)
#define OFF_PACK ((size_t)13385728)

// pack sub-offsets (shorts)
#define PK_A  0
#define PK_G  65536
#define PK_M  131072
#define PK_Z  196608
#define PK_R  245760
#define PK_H  294912
#define PK_O  344064

typedef short bf16x8 __attribute__((ext_vector_type(8)));
typedef float f32x4 __attribute__((ext_vector_type(4)));
typedef unsigned int u32x2 __attribute__((ext_vector_type(2)));

#define MFMA(a, b, c) __builtin_amdgcn_mfma_f32_16x16x32_bf16((a), (b), (c), 0, 0, 0)

// barrier WITHOUT vmcnt drain: LDS handoff only; global loads stay in flight.
#define SYNCW() do { \
    __builtin_amdgcn_sched_barrier(0); \
    asm volatile("s_waitcnt lgkmcnt(0)" ::: "memory"); \
    __builtin_amdgcn_s_barrier(); \
    __builtin_amdgcn_sched_barrier(0); \
} while (0)

__device__ __forceinline__ float gelu_tanh(float v) {
    const float c = 0.7978845608028654f;
    float t = tanhf(c * (v + 0.044715f * v * v * v));
    return 0.5f * v * (1.0f + t);
}
__device__ __forceinline__ float softplus_f(float x) {
    if (x > 20.0f) return x;
    return log1pf(expf(x));
}
__device__ __forceinline__ short f2bf_s(float f) {
    unsigned u = __float_as_uint(f);
    u += 0x7fffu + ((u >> 16) & 1u);
    return (short)(u >> 16);
}
__device__ __forceinline__ unsigned pk_bf(float a, float b) {
    return ((unsigned)(unsigned short)f2bf_s(b) << 16) | (unsigned)(unsigned short)f2bf_s(a);
}
// round-5 numerics: libm-based sigmoid/tanh (bisection: revert hw v_exp/v_rcp)
__device__ __forceinline__ f32x4 sig4(f32x4 x) {
    f32x4 o;
#pragma unroll
    for (int i = 0; i < 4; ++i)
        o[i] = 1.0f / (1.0f + expf(-x[i]));
    return o;
}
__device__ __forceinline__ f32x4 tanh4(f32x4 x) {
    f32x4 o;
#pragma unroll
    for (int i = 0; i < 4; ++i)
        o[i] = tanhf(x[i]);
    return o;
}
// pack f32x4 -> 4 bf16 (explicit RNE) and store 8 bytes (bisection: revert cvt_pk)
__device__ __forceinline__ void st_bf4(char* base, int stride, int row, int byteoff,
                                       const f32x4& v) {
    u32x2 p;
    p[0] = pk_bf(v[0], v[1]);
    p[1] = pk_bf(v[2], v[3]);
    *(u32x2*)(base + row * stride + byteoff) = p;
}

// activation B-frag read: lane l -> row (l&15), k-bytes ks*64 + (l>>4)*16
#define BFRAG(buf, STR, ks) (*(const bf16x8*)((buf) + (l & 15) * (STR) + (ks) * 64 + (l >> 4) * 16))
// weight A-frag from global pack
#define GFRAG(p, fi) (*(const bf16x8*)((p) + ((size_t)(fi) * 64 + l) * 8))
// weight A-frag from LDS stage (frag stride 1024 B)
#define LFRAG(buf, fi) (*(const bf16x8*)((buf) + (size_t)(fi) * 1024 + l * 16))

// ---- P/K covariance recurrence (data-independent) ----
__global__ __launch_bounds__(512) void k_precompute(const float* __restrict__ Q,
                                                    const float* __restrict__ R,
                                                    float* __restrict__ Kt) {
    __shared__ float red[512];
    __shared__ float r_eff_sh;
    const int t = threadIdx.x;
    red[t] = softplus_f(R[t]);
    __syncthreads();
    for (int s = 256; s > 0; s >>= 1) {
        if (t < s) red[t] += red[t + s];
        __syncthreads();
    }
    if (t == 0) r_eff_sh = red[0] / 512.0f;
    __syncthreads();
    const float r_eff = r_eff_sh;
    if (t < NS) {
        const float q = softplus_f(Q[t]);
        float P = 1.0f;
        for (int step = 0; step < NT; ++step) {
            float Pp = fminf(fmaxf(P + q, 1e-6f), 10.0f);
            float K  = fminf(fmaxf(Pp / (Pp + r_eff + 1e-6f), 0.0f), 1.0f);
            Kt[(size_t)step * NS + t] = K;
            P = fminf(fmaxf(Pp * (1.0f - K), 1e-6f), 10.0f);
        }
    }
}

// ---- generic transpose ----
__global__ void k_transpose(const float* __restrict__ in, float* __restrict__ outp,
                            int Rr, int Cc) {
    int i = blockIdx.x * 256 + threadIdx.x;
    if (i < Rr * Cc) {
        int r = i / Cc, c = i % Cc;
        outp[(size_t)c * Rr + r] = in[i];
    }
}

// ---- IG = I - G*diag(Kinf) ----
__global__ void k_ig(const float* __restrict__ G, const float* __restrict__ Kt,
                     float* __restrict__ IG) {
    int i = blockIdx.x * 256 + threadIdx.x;
    if (i >= NS * NS) return;
    int r = i >> 8, c = i & 255;
    float kinf = Kt[(size_t)(NT - 1) * NS + c];
    IG[i] = ((r == c) ? 1.0f : 0.0f) - G[i] * kinf;
}

// ---- ustate3[t][m][s] = us + K_t*(Hu - usG) ----
__global__ void k_fuse(const float* __restrict__ us, const float* __restrict__ usG,
                       const float* __restrict__ Hu, const float* __restrict__ Kt,
                       float* __restrict__ u3) {
    int i = blockIdx.x * 256 + threadIdx.x;
    if (i >= NT * NB * NS) return;
    int s = i & 255;
    int tm = i >> 8;
    int m = tm & 15, t = tm >> 4;
    size_t src = ((size_t)m * NT + t) * NS + s;
    float k = Kt[(size_t)t * NS + s];
    u3[i] = us[src] + k * (Hu[src] - usG[src]);
}

// ---- pack W[K][N] f32 -> bf16 MFMA fragments (tile nt-major, ks-minor) ----
__global__ void k_pack(const float* __restrict__ W, short* __restrict__ dst, int K, int N) {
    int f = blockIdx.x * 256 + threadIdx.x;
    if (f >= K * N) return;
    const int j = f & 7, l = (f >> 3) & 63, tile = f >> 9;
    const int KS = K >> 5;
    const int nt = tile / KS, ks = tile - nt * KS;
    const int k = ks * 32 + (l >> 4) * 8 + j;
    const int n = nt * 16 + (l & 15);
    dst[f] = f2bf_s(W[(size_t)k * N + n]);
}

// ---- f32 tiled GEMM ----
__global__ __launch_bounds__(256) void k_gemm(const float* __restrict__ Am,
                                              const float* __restrict__ Bm,
                                              const float* __restrict__ bias,
                                              const float* __restrict__ resid,
                                              float* __restrict__ Cm,
                                              int M, int N, int K, int act) {
    __shared__ __align__(16) float As[16][68];
    __shared__ __align__(16) float Bs[16][68];
    const int tid = threadIdx.x;
    const int bn = blockIdx.x, bm = blockIdx.y;
    const int row0 = bm * 64, col0 = bn * 64;
    const int tx = tid & 15, ty = tid >> 4;
    const int ar = tid >> 2, ac = (tid & 3) << 2;
    const int bk = tid >> 4, bc = (tid & 15) << 2;

    float acc[4][4];
#pragma unroll
    for (int i = 0; i < 4; ++i)
#pragma unroll
        for (int j = 0; j < 4; ++j) acc[i][j] = 0.0f;

    for (int k0 = 0; k0 < K; k0 += 16) {
        float4 av = *(const float4*)(Am + (size_t)(row0 + ar) * K + k0 + ac);
        float4 bv = *(const float4*)(Bm + (size_t)(k0 + bk) * N + col0 + bc);
        As[ac + 0][ar] = av.x; As[ac + 1][ar] = av.y;
        As[ac + 2][ar] = av.z; As[ac + 3][ar] = av.w;
        *(float4*)&Bs[bk][bc] = bv;
        __syncthreads();
#pragma unroll
        for (int kk = 0; kk < 16; ++kk) {
            const float a0 = As[kk][ty * 4 + 0], a1 = As[kk][ty * 4 + 1];
            const float a2 = As[kk][ty * 4 + 2], a3 = As[kk][ty * 4 + 3];
            const float4 b4 = *(const float4*)&Bs[kk][tx * 4];
            acc[0][0] += a0 * b4.x; acc[0][1] += a0 * b4.y; acc[0][2] += a0 * b4.z; acc[0][3] += a0 * b4.w;
            acc[1][0] += a1 * b4.x; acc[1][1] += a1 * b4.y; acc[1][2] += a1 * b4.z; acc[1][3] += a1 * b4.w;
            acc[2][0] += a2 * b4.x; acc[2][1] += a2 * b4.y; acc[2][2] += a2 * b4.z; acc[2][3] += a2 * b4.w;
            acc[3][0] += a3 * b4.x; acc[3][1] += a3 * b4.y; acc[3][2] += a3 * b4.z; acc[3][3] += a3 * b4.w;
        }
        __syncthreads();
    }
#pragma unroll
    for (int i = 0; i < 4; ++i) {
        const int r = row0 + ty * 4 + i;
#pragma unroll
        for (int j = 0; j < 4; ++j) {
            const int c = col0 + tx * 4 + j;
            float v = acc[i][j];
            if (bias) v += bias[c];
            if (act) v = gelu_tanh(v);
            if (resid) v += resid[(size_t)r * N + c];
            Cm[(size_t)r * N + c] = v;
        }
    }
}

// =====================================================================
// MFMA scan, operand-swapped (weights=A, activations=B): m in lane dim,
// zero cross-lane shuffles. Round-5 numerics (f2bf_s RNE, expf/tanhf).
// 4 barriers/step, 60 MFMA/wave/step.
// Regs: Minf(64) Wzx(32) Wrx(32) Wzh(16) Wrh(16) Wout(32) = 192.
// LDS: Wh full (96K) + XE/XT(8.25K ea) + HB/RG(4.25K ea) = 121 KB.
// =====================================================================
#define XE_STR 528   // 256 bf16 + 16B pad (odd-16B stride)
#define HB_STR 272   // 128 bf16 + 16B pad

__global__ __launch_bounds__(512, 2) void k_scan_mfma(
    const short* __restrict__ pM, const short* __restrict__ pA, const short* __restrict__ pG,
    const short* __restrict__ pZ, const short* __restrict__ pR, const short* __restrict__ pH,
    const short* __restrict__ pO,
    const float* __restrict__ bz, const float* __restrict__ br, const float* __restrict__ bh,
    const float* __restrict__ us, const float* __restrict__ Hu, const float* __restrict__ u3,
    const float* __restrict__ Kt, float* __restrict__ xs)
{
    __shared__ __align__(16) char XE[16 * XE_STR];   // x_est carry
    __shared__ __align__(16) char XT[16 * XE_STR];   // x_pred / x_post staging
    __shared__ __align__(16) char HBs[16 * HB_STR];  // h carry
    __shared__ __align__(16) char RGs[16 * HB_STR];  // r*h
    __shared__ __align__(16) char WHH[96 * 1024];    // full Wh frags (12/wave)

    const int tid = threadIdx.x, w = tid >> 6, l = tid & 63;
    const int m = l & 15, lg = l >> 4;
    const int c0 = 32 * w + 4 * lg;   // state col base (tile 2w); second tile at +16
    const int cg = 16 * w + 4 * lg;   // gru col base

    for (int i = tid; i < (16 * XE_STR) / 4; i += 512) ((int*)XE)[i] = 0;
    for (int i = tid; i < (16 * HB_STR) / 4; i += 512) ((int*)HBs)[i] = 0;
    for (int i = tid; i < 6144; i += 512) ((int4*)WHH)[i] = ((const int4*)pH)[i];

    const f32x4 bzv = *(const f32x4*)(bz + cg);
    const f32x4 brv = *(const f32x4*)(br + cg);
    const f32x4 bhv = *(const f32x4*)(bh + cg);
    f32x4 hFr = {0.f, 0.f, 0.f, 0.f};
    __syncthreads();

    // ---------------- early phase t<T0: exact per-t K, streamed weights ----------------
    for (int t = 0; t < T0; ++t) {
        const float* usb = us + ((size_t)m * NT + t) * NS;
        const float* hub = Hu + ((size_t)m * NT + t) * NS;
        const float* ktb = Kt + (size_t)t * NS;
        f32x4 us0 = *(const f32x4*)(usb + c0), us1 = *(const f32x4*)(usb + c0 + 16);
        f32x4 hu0 = *(const f32x4*)(hub + c0), hu1 = *(const f32x4*)(hub + c0 + 16);
        f32x4 kv0 = *(const f32x4*)(ktb + c0), kv1 = *(const f32x4*)(ktb + c0 + 16);
        // E1: x_pred = x_est@A^T + us  -> XT
        f32x4 p0 = {0.f,0.f,0.f,0.f}, p1 = {0.f,0.f,0.f,0.f};
#pragma unroll
        for (int ks = 0; ks < 8; ++ks) {
            bf16x8 xe = BFRAG(XE, XE_STR, ks);
            p0 = MFMA(GFRAG(pA, (2 * w + 0) * 8 + ks), xe, p0);
            p1 = MFMA(GFRAG(pA, (2 * w + 1) * 8 + ks), xe, p1);
        }
        p0 += us0; p1 += us1;
        st_bf4(XT, XE_STR, m, c0 * 2, p0);
        st_bf4(XT, XE_STR, m, (c0 + 16) * 2, p1);
        SYNCW();
        // E2: g = x_pred@G ; x_post = x_pred + K*(Hu - g)  -> XE
        f32x4 g0 = {0.f,0.f,0.f,0.f}, g1 = {0.f,0.f,0.f,0.f};
#pragma unroll
        for (int ks = 0; ks < 8; ++ks) {
            bf16x8 xt = BFRAG(XT, XE_STR, ks);
            g0 = MFMA(GFRAG(pG, (2 * w + 0) * 8 + ks), xt, g0);
            g1 = MFMA(GFRAG(pG, (2 * w + 1) * 8 + ks), xt, g1);
        }
        f32x4 xq0 = p0 + kv0 * (hu0 - g0);
        f32x4 xq1 = p1 + kv1 * (hu1 - g1);
        st_bf4(XE, XE_STR, m, c0 * 2, xq0);
        st_bf4(XE, XE_STR, m, (c0 + 16) * 2, xq1);
        SYNCW();
        // E3: gates over [h | x_post]
        f32x4 za = bzv, ra = brv, hx = bhv;
#pragma unroll
        for (int ks = 0; ks < 4; ++ks) {
            bf16x8 hb = BFRAG(HBs, HB_STR, ks);
            za = MFMA(GFRAG(pZ, w * 12 + ks), hb, za);
            ra = MFMA(GFRAG(pR, w * 12 + ks), hb, ra);
        }
#pragma unroll
        for (int ks = 0; ks < 8; ++ks) {
            bf16x8 xef = BFRAG(XE, XE_STR, ks);
            za = MFMA(GFRAG(pZ, w * 12 + 4 + ks), xef, za);
            ra = MFMA(GFRAG(pR, w * 12 + 4 + ks), xef, ra);
            hx = MFMA(GFRAG(pH, w * 12 + 4 + ks), xef, hx);
        }
        f32x4 z = sig4(za), r = sig4(ra), rg = r * hFr;
        st_bf4(RGs, HB_STR, m, cg * 2, rg);
        SYNCW();
        // E4: hc = tanh(rg@Wh_h + hx); h update
        f32x4 hc = hx;
#pragma unroll
        for (int ks = 0; ks < 4; ++ks)
            hc = MFMA(GFRAG(pH, w * 12 + ks), BFRAG(RGs, HB_STR, ks), hc);
        f32x4 hcv = tanh4(hc);
        f32x4 hn = hFr + z * (hcv - hFr);
        hFr = hn;
        st_bf4(HBs, HB_STR, m, cg * 2, hn);
        SYNCW();
        // E5: x_final = x_post + h@Wout  -> XE, xs
#pragma unroll
        for (int ks = 0; ks < 4; ++ks) {
            bf16x8 hb2 = BFRAG(HBs, HB_STR, ks);
            xq0 = MFMA(GFRAG(pO, (2 * w + 0) * 4 + ks), hb2, xq0);
            xq1 = MFMA(GFRAG(pO, (2 * w + 1) * 4 + ks), hb2, xq1);
        }
        st_bf4(XE, XE_STR, m, c0 * 2, xq0);
        st_bf4(XE, XE_STR, m, (c0 + 16) * 2, xq1);
        {
            float* xb = xs + ((size_t)m * NT + t) * NS;
            *(f32x4*)(xb + c0) = xq0;
            *(f32x4*)(xb + c0 + 16) = xq1;
        }
        SYNCW();
    }

    // ---------------- register weights for main loop ----------------
    bf16x8 rM0[8], rM1[8], rZx[8], rRx[8], rZh[4], rRh[4], rO0[4], rO1[4];
#pragma unroll
    for (int ks = 0; ks < 8; ++ks) {
        rM0[ks] = GFRAG(pM, (2 * w + 0) * 8 + ks);
        rM1[ks] = GFRAG(pM, (2 * w + 1) * 8 + ks);
        rZx[ks] = GFRAG(pZ, w * 12 + 4 + ks);
        rRx[ks] = GFRAG(pR, w * 12 + 4 + ks);
    }
#pragma unroll
    for (int ks = 0; ks < 4; ++ks) {
        rZh[ks] = GFRAG(pZ, w * 12 + ks);
        rRh[ks] = GFRAG(pR, w * 12 + ks);
        rO0[ks] = GFRAG(pO, (2 * w + 0) * 4 + ks);
        rO1[ks] = GFRAG(pO, (2 * w + 1) * 4 + ks);
    }

    // initial h-gate carries from h_{T0-1}: zh = bz + h@Wz_h (exact, h static here)
    f32x4 zh = bzv, rh = brv;
#pragma unroll
    for (int ks = 0; ks < 4; ++ks) {
        bf16x8 hb = BFRAG(HBs, HB_STR, ks);
        zh = MFMA(rZh[ks], hb, zh);
        rh = MFMA(rRh[ks], hb, rh);
    }

    // ---------------- main loop: 4 barriers/step ----------------
    for (int t = T0; t < NT; ++t) {
        const float* ubase = u3 + ((size_t)(t * NB) + m) * NS;
        f32x4 cu0 = *(const f32x4*)(ubase + c0);
        f32x4 cu1 = *(const f32x4*)(ubase + c0 + 16);

        // ph1: x_post = x_est@Minf + u3  -> XT
        f32x4 xq0 = {0.f,0.f,0.f,0.f}, xq1 = {0.f,0.f,0.f,0.f};
#pragma unroll
        for (int ks = 0; ks < 8; ++ks) {
            bf16x8 xe = BFRAG(XE, XE_STR, ks);
            xq0 = MFMA(rM0[ks], xe, xq0);
            xq1 = MFMA(rM1[ks], xe, xq1);
        }
        xq0 += cu0; xq1 += cu1;
        st_bf4(XT, XE_STR, m, c0 * 2, xq0);
        st_bf4(XT, XE_STR, m, (c0 + 16) * 2, xq1);
        SYNCW();  // bar A
        // ph2: gates exact from x_post (XT) + h-carry
        f32x4 za = zh, ra = rh, hx = bhv;
#pragma unroll
        for (int ks = 0; ks < 8; ++ks) {
            bf16x8 xt = BFRAG(XT, XE_STR, ks);
            za = MFMA(rZx[ks], xt, za);
            ra = MFMA(rRx[ks], xt, ra);
            hx = MFMA(LFRAG(WHH, w * 12 + 4 + ks), xt, hx);
        }
        f32x4 z = sig4(za), r = sig4(ra), rg = r * hFr;
        st_bf4(RGs, HB_STR, m, cg * 2, rg);
        SYNCW();  // bar B
        // ph3: hc = tanh(rg@Wh_h + hx); h update
        f32x4 hc = hx;
#pragma unroll
        for (int ks = 0; ks < 4; ++ks)
            hc = MFMA(LFRAG(WHH, w * 12 + ks), BFRAG(RGs, HB_STR, ks), hc);
        f32x4 hcv = tanh4(hc);
        f32x4 hn = hFr + z * (hcv - hFr);
        hFr = hn;
        st_bf4(HBs, HB_STR, m, cg * 2, hn);
        SYNCW();  // bar C
        // ph4: x_final = x_post + h@Wout ; next-step h-gate carries (exact)
        f32x4 zhN = bzv, rhN = brv;
#pragma unroll
        for (int ks = 0; ks < 4; ++ks) {
            bf16x8 hb2 = BFRAG(HBs, HB_STR, ks);
            xq0 = MFMA(rO0[ks], hb2, xq0);
            xq1 = MFMA(rO1[ks], hb2, xq1);
            zhN = MFMA(rZh[ks], hb2, zhN);
            rhN = MFMA(rRh[ks], hb2, rhN);
        }
        st_bf4(XE, XE_STR, m, c0 * 2, xq0);
        st_bf4(XE, XE_STR, m, (c0 + 16) * 2, xq1);
        {
            float* xb = xs + ((size_t)m * NT + t) * NS;
            *(f32x4*)(xb + c0) = xq0;
            *(f32x4*)(xb + c0 + 16) = xq1;
        }
        zh = zhN; rh = rhN;
        SYNCW();  // bar D
    }
}

extern "C" void kernel_launch(void* const* d_in, const int* in_sizes, int n_in,
                              void* d_out, int out_size, void* d_ws, size_t ws_size,
                              hipStream_t stream) {
    (void)in_sizes; (void)n_in; (void)out_size; (void)ws_size;
    const float* x       = (const float*)d_in[0];
    const float* W_in    = (const float*)d_in[1];
    const float* b_in    = (const float*)d_in[2];
    const float* W_state = (const float*)d_in[3];
    const float* b_state = (const float*)d_in[4];
    const float* A       = (const float*)d_in[5];
    const float* H       = (const float*)d_in[6];
    const float* Q       = (const float*)d_in[7];
    const float* R       = (const float*)d_in[8];
    const float* W_z     = (const float*)d_in[9];
    const float* W_r     = (const float*)d_in[10];
    const float* W_h     = (const float*)d_in[11];
    const float* b_z     = (const float*)d_in[12];
    const float* b_r     = (const float*)d_in[13];
    const float* b_h     = (const float*)d_in[14];
    const float* W_out   = (const float*)d_in[15];
    const float* W_outp  = (const float*)d_in[16];
    const float* b_outp  = (const float*)d_in[17];
    float* out = (float*)d_out;
    float* w = (float*)d_ws;

    float* us   = w + OFF_US;
    float* Hu   = w + OFF_HU;
    float* u3   = w + OFF_U3;
    float* Kt   = w + OFF_KT;
    float* Ht   = w + OFF_HT;
    float* At   = w + OFF_AT;
    float* G    = w + OFF_G;
    float* IG   = w + OFF_IG;
    float* Minf = w + OFF_MINF;
    float* Wzt  = w + OFF_WZT;
    float* Wrt  = w + OFF_WRT;
    float* Wht  = w + OFF_WHT;
    short* pk   = (short*)(w + OFF_PACK);

    float* usG = out;                        // d_out lower half (scratch, dead after fuse)
    float* u   = out + (size_t)8388608;      // d_out upper half
    float* xs  = out + (size_t)8388608;      // overwrites u (dead pre-scan)
    float* obs = w + OFF_US;                 // us+Hu region (dead after scan)

    const int M = NB * NT;  // 16384

    hipLaunchKernelGGL(k_precompute, dim3(1), dim3(512), 0, stream, Q, R, Kt);
    hipLaunchKernelGGL(k_transpose, dim3((NS * NS + 255) / 256), dim3(256), 0, stream, A, At, NS, NS);
    hipLaunchKernelGGL(k_transpose, dim3((ND * NS + 255) / 256), dim3(256), 0, stream, H, Ht, ND, NS);
    hipLaunchKernelGGL(k_transpose, dim3((NH * 384 + 255) / 256), dim3(256), 0, stream, W_z, Wzt, NH, 384);
    hipLaunchKernelGGL(k_transpose, dim3((NH * 384 + 255) / 256), dim3(256), 0, stream, W_r, Wrt, NH, 384);
    hipLaunchKernelGGL(k_transpose, dim3((NH * 384 + 255) / 256), dim3(256), 0, stream, W_h, Wht, NH, 384);
    // u = gelu(x @ W_in + b_in)
    hipLaunchKernelGGL(k_gemm, dim3(ND / 64, M / 64), dim3(256), 0, stream,
                       x, W_in, b_in, nullptr, u, M, ND, NE, 1);
    // us = u @ W_state + b_state
    hipLaunchKernelGGL(k_gemm, dim3(NS / 64, M / 64), dim3(256), 0, stream,
                       u, W_state, b_state, nullptr, us, M, NS, ND, 0);
    // Hu = u @ H
    hipLaunchKernelGGL(k_gemm, dim3(NS / 64, M / 64), dim3(256), 0, stream,
                       u, H, nullptr, nullptr, Hu, M, NS, ND, 0);
    // G = H^T @ H
    hipLaunchKernelGGL(k_gemm, dim3(NS / 64, NS / 64), dim3(256), 0, stream,
                       Ht, H, nullptr, nullptr, G, NS, NS, ND, 0);
    // usG = us @ G
    hipLaunchKernelGGL(k_gemm, dim3(NS / 64, M / 64), dim3(256), 0, stream,
                       us, G, nullptr, nullptr, usG, M, NS, NS, 0);
    // IG = I - G diag(Kinf); Minf = At @ IG
    hipLaunchKernelGGL(k_ig, dim3(256), dim3(256), 0, stream, G, Kt, IG);
    hipLaunchKernelGGL(k_gemm, dim3(NS / 64, NS / 64), dim3(256), 0, stream,
                       At, IG, nullptr, nullptr, Minf, NS, NS, NS, 0);
    // u3 = us + K.*(Hu - usG)
    hipLaunchKernelGGL(k_fuse, dim3((NT * NB * NS) / 256), dim3(256), 0, stream,
                       us, usG, Hu, Kt, u3);
    // packs
    hipLaunchKernelGGL(k_pack, dim3((NS * NS + 255) / 256), dim3(256), 0, stream, At, pk + PK_A, NS, NS);
    hipLaunchKernelGGL(k_pack, dim3((NS * NS + 255) / 256), dim3(256), 0, stream, G, pk + PK_G, NS, NS);
    hipLaunchKernelGGL(k_pack, dim3((NS * NS + 255) / 256), dim3(256), 0, stream, Minf, pk + PK_M, NS, NS);
    hipLaunchKernelGGL(k_pack, dim3((384 * NH + 255) / 256), dim3(256), 0, stream, Wzt, pk + PK_Z, 384, NH);
    hipLaunchKernelGGL(k_pack, dim3((384 * NH + 255) / 256), dim3(256), 0, stream, Wrt, pk + PK_R, 384, NH);
    hipLaunchKernelGGL(k_pack, dim3((384 * NH + 255) / 256), dim3(256), 0, stream, Wht, pk + PK_H, 384, NH);
    hipLaunchKernelGGL(k_pack, dim3((NH * NS + 255) / 256), dim3(256), 0, stream, W_out, pk + PK_O, NH, NS);
    // scan
    hipLaunchKernelGGL(k_scan_mfma, dim3(1), dim3(512), 0, stream,
                       pk + PK_M, pk + PK_A, pk + PK_G, pk + PK_Z, pk + PK_R, pk + PK_H,
                       pk + PK_O,
                       b_z, b_r, b_h, us, Hu, u3, Kt, xs);
    // obs = xs @ H^T
    hipLaunchKernelGGL(k_gemm, dim3(ND / 64, M / 64), dim3(256), 0, stream,
                       xs, Ht, nullptr, nullptr, obs, M, ND, NS, 0);
    // out = obs @ W_outp + b_outp + x
    hipLaunchKernelGGL(k_gemm, dim3(NE / 64, M / 64), dim3(256), 0, stream,
                       obs, W_outp, b_outp, x, out, M, NE, ND, 0);
}

// Round 9
// 3267.358 us; speedup vs baseline: 2.1898x; 1.4085x over previous
//
#include <hip/hip_runtime.h>
#include <cstdint>
#include <cstddef>

// Problem dims
#define NB 16
#define NT 1024
#define NE 1024
#define NS 256
#define ND 512
#define NH 128
#define T0 16

// ---- ws layout (float offsets) ----
#define OFF_US   ((size_t)0)
#define OFF_HU   ((size_t)4194304)
#define OFF_U3   ((size_t)8388608)
#define OFF_KT   ((size_t)12582912)
#define OFF_HT   ((size_t)12845056)
#define OFF_AT   ((size_t)12976128)
#define OFF_G    ((size_t)13041664)
#define OFF_IG   ((size_t)13107200)
#define OFF_MINF ((size_t)13172736)
#define OFF_WZT  ((size_t)13238272)
#define OFF_WRT  ((size_t)13287424)
#define OFF_WHT  ((size_t)13336576)
#define OFF_HTWO ((size_t)13385728)   // 256*1024
#define OFF_PACK ((size_t)13647872)   // shorts region, 1425408 shorts
#define OFF_XSPK ((size_t)14360576)   // 4194304 shorts -> ws end 16457728 fl (65.8MB)

// pack sub-offsets (shorts)
#define PK_A   0
#define PK_G   65536
#define PK_M   131072
#define PK_Z   196608
#define PK_R   245760
#define PK_H   294912
#define PK_O   344064
#define PK_WIN 376832
#define PK_WST 901120
#define PK_HM  1032192
#define PK_HTW 1163264

// d_out scratch (floats): [0..8.39M) x_pk -> u_pk -> us_pk ; usG f32 at [4.19M..8.39M)
//                         [8.39M..16.78M) u f32 -> xs f32. Final GEMM overwrites all.

typedef short bf16x8 __attribute__((ext_vector_type(8)));
typedef float f32x4 __attribute__((ext_vector_type(4)));
typedef unsigned int u32x2 __attribute__((ext_vector_type(2)));

#define MFMA(a, b, c) __builtin_amdgcn_mfma_f32_16x16x32_bf16((a), (b), (c), 0, 0, 0)

// barrier WITHOUT vmcnt drain
#define SYNCW() do { \
    __builtin_amdgcn_sched_barrier(0); \
    asm volatile("s_waitcnt lgkmcnt(0)" ::: "memory"); \
    __builtin_amdgcn_s_barrier(); \
    __builtin_amdgcn_sched_barrier(0); \
} while (0)

__device__ __forceinline__ float gelu_tanh(float v) {
    const float c = 0.7978845608028654f;
    float t = tanhf(c * (v + 0.044715f * v * v * v));
    return 0.5f * v * (1.0f + t);
}
__device__ __forceinline__ float softplus_f(float x) {
    if (x > 20.0f) return x;
    return log1pf(expf(x));
}
__device__ __forceinline__ short f2bf_s(float f) {
    unsigned u = __float_as_uint(f);
    u += 0x7fffu + ((u >> 16) & 1u);
    return (short)(u >> 16);
}
__device__ __forceinline__ unsigned pk_bf(float a, float b) {
    return ((unsigned)(unsigned short)f2bf_s(b) << 16) | (unsigned)(unsigned short)f2bf_s(a);
}
__device__ __forceinline__ float exp2_hw(float x) {
    float r; asm("v_exp_f32 %0, %1" : "=v"(r) : "v"(x)); return r;
}
__device__ __forceinline__ float rcp_hw(float x) {
    float r; asm("v_rcp_f32 %0, %1" : "=v"(r) : "v"(x)); return r;
}
// hw sigmoid/tanh (bisect: f2bf_s RNE packing kept everywhere)
__device__ __forceinline__ f32x4 sig4(f32x4 x) {
    f32x4 o;
#pragma unroll
    for (int i = 0; i < 4; ++i)
        o[i] = rcp_hw(1.0f + exp2_hw(-1.442695040888963f * x[i]));
    return o;
}
__device__ __forceinline__ f32x4 tanh4(f32x4 x) {
    f32x4 o;
#pragma unroll
    for (int i = 0; i < 4; ++i) {
        float e = exp2_hw(2.885390081777927f * x[i]);
        o[i] = 1.0f - 2.0f * rcp_hw(e + 1.0f);
    }
    return o;
}
// pack f32x4 -> 4 bf16 (explicit RNE) and store 8 bytes
__device__ __forceinline__ void st_bf4(char* base, int stride, int row, int byteoff,
                                       const f32x4& v) {
    u32x2 p;
    p[0] = pk_bf(v[0], v[1]);
    p[1] = pk_bf(v[2], v[3]);
    *(u32x2*)(base + row * stride + byteoff) = p;
}

#define BFRAG(buf, STR, ks) (*(const bf16x8*)((buf) + (l & 15) * (STR) + (ks) * 64 + (l >> 4) * 16))
#define GFRAG(p, fi) (*(const bf16x8*)((p) + ((size_t)(fi) * 64 + l) * 8))
#define LFRAG(buf, fi) (*(const bf16x8*)((buf) + (size_t)(fi) * 1024 + l * 16))

// ---- P/K covariance recurrence ----
__global__ __launch_bounds__(512) void k_precompute(const float* __restrict__ Q,
                                                    const float* __restrict__ R,
                                                    float* __restrict__ Kt) {
    __shared__ float red[512];
    __shared__ float r_eff_sh;
    const int t = threadIdx.x;
    red[t] = softplus_f(R[t]);
    __syncthreads();
    for (int s = 256; s > 0; s >>= 1) {
        if (t < s) red[t] += red[t + s];
        __syncthreads();
    }
    if (t == 0) r_eff_sh = red[0] / 512.0f;
    __syncthreads();
    const float r_eff = r_eff_sh;
    if (t < NS) {
        const float q = softplus_f(Q[t]);
        float P = 1.0f;
        for (int step = 0; step < NT; ++step) {
            float Pp = fminf(fmaxf(P + q, 1e-6f), 10.0f);
            float K  = fminf(fmaxf(Pp / (Pp + r_eff + 1e-6f), 0.0f), 1.0f);
            Kt[(size_t)step * NS + t] = K;
            P = fminf(fmaxf(Pp * (1.0f - K), 1e-6f), 10.0f);
        }
    }
}

__global__ void k_transpose(const float* __restrict__ in, float* __restrict__ outp,
                            int Rr, int Cc) {
    int i = blockIdx.x * 256 + threadIdx.x;
    if (i < Rr * Cc) {
        int r = i / Cc, c = i % Cc;
        outp[(size_t)c * Rr + r] = in[i];
    }
}

__global__ void k_ig(const float* __restrict__ G, const float* __restrict__ Kt,
                     float* __restrict__ IG) {
    int i = blockIdx.x * 256 + threadIdx.x;
    if (i >= NS * NS) return;
    int r = i >> 8, c = i & 255;
    float kinf = Kt[(size_t)(NT - 1) * NS + c];
    IG[i] = ((r == c) ? 1.0f : 0.0f) - G[i] * kinf;
}

__global__ void k_fuse(const float* __restrict__ us, const float* __restrict__ usG,
                       const float* __restrict__ Hu, const float* __restrict__ Kt,
                       float* __restrict__ u3) {
    int i = blockIdx.x * 256 + threadIdx.x;
    if (i >= NT * NB * NS) return;
    int s = i & 255;
    int tm = i >> 8;
    int m = tm & 15, t = tm >> 4;
    size_t src = ((size_t)m * NT + t) * NS + s;
    float k = Kt[(size_t)t * NS + s];
    u3[i] = us[src] + k * (Hu[src] - usG[src]);
}

// ---- pack W[K][N] f32 -> bf16 B-operand frags ----
__global__ void k_pack(const float* __restrict__ W, short* __restrict__ dst, int K, int N) {
    int f = blockIdx.x * 256 + threadIdx.x;
    if (f >= K * N) return;
    const int j = f & 7, l = (f >> 3) & 63, tile = f >> 9;
    const int KS = K >> 5;
    const int nt = tile / KS, ks = tile - nt * KS;
    const int k = ks * 32 + (l >> 4) * 8 + j;
    const int n = nt * 16 + (l & 15);
    dst[f] = f2bf_s(W[(size_t)k * N + n]);
}

// ---- pack A[M][K] f32 -> bf16 A-operand frags (BFRAG-layout) ----
__global__ void k_packA(const float* __restrict__ A, short* __restrict__ dst,
                        int K, int total) {
    int f = blockIdx.x * 256 + threadIdx.x;
    if (f >= total) return;
    const int j = f & 7, l = (f >> 3) & 63, tile = f >> 9;
    const int KS = K >> 5;
    const int mt = tile / KS, ks = tile - mt * KS;
    dst[f] = f2bf_s(A[(size_t)(mt * 16 + (l & 15)) * K + ks * 32 + (l >> 4) * 8 + j]);
}

// ---- bf16 MFMA GEMM: C[M,N] = act(Apk@Bpk + bias) + resid, f32 out ----
// block: 4 waves; wave w -> m-tile blockIdx.x*4+w; n: blockIdx.y*128, 8 tiles
__global__ __launch_bounds__(256) void k_mm(const short* __restrict__ Apk,
                                            const short* __restrict__ Bpk,
                                            const float* __restrict__ bias,
                                            const float* __restrict__ resid,
                                            float* __restrict__ C,
                                            int N, int K, int act) {
    const int tid = threadIdx.x, w = tid >> 6, l = tid & 63;
    const int KS = K >> 5;
    const int mt = blockIdx.x * 4 + w;
    const int nt0 = blockIdx.y * 8;
    f32x4 acc[8];
#pragma unroll
    for (int j = 0; j < 8; ++j) acc[j] = (f32x4){0.f, 0.f, 0.f, 0.f};
    for (int ks = 0; ks < KS; ++ks) {
        bf16x8 a = *(const bf16x8*)(Apk + ((size_t)(mt * KS + ks) * 64 + l) * 8);
#pragma unroll
        for (int j = 0; j < 8; ++j) {
            bf16x8 b = *(const bf16x8*)(Bpk + ((size_t)(nt0 + j) * KS + ks) * 512 + (size_t)l * 8);
            acc[j] = MFMA(b, a, acc[j]);
        }
    }
    const int m = mt * 16 + (l & 15);
    const int lg = l >> 4;
#pragma unroll
    for (int j = 0; j < 8; ++j) {
        const int n = (nt0 + j) * 16 + lg * 4;
        f32x4 v = acc[j];
        if (bias) v += *(const f32x4*)(bias + n);
        if (act) {
#pragma unroll
            for (int r = 0; r < 4; ++r) v[r] = gelu_tanh(v[r]);
        }
        if (resid) v += *(const f32x4*)(resid + (size_t)m * N + n);
        *(f32x4*)(C + (size_t)m * N + n) = v;
    }
}

// ---- f32 tiled GEMM (small exact matrices: G, Minf, HtWo) ----
__global__ __launch_bounds__(256) void k_gemm(const float* __restrict__ Am,
                                              const float* __restrict__ Bm,
                                              const float* __restrict__ bias,
                                              const float* __restrict__ resid,
                                              float* __restrict__ Cm,
                                              int M, int N, int K, int act) {
    __shared__ __align__(16) float As[16][68];
    __shared__ __align__(16) float Bs[16][68];
    const int tid = threadIdx.x;
    const int bn = blockIdx.x, bm = blockIdx.y;
    const int row0 = bm * 64, col0 = bn * 64;
    const int tx = tid & 15, ty = tid >> 4;
    const int ar = tid >> 2, ac = (tid & 3) << 2;
    const int bk = tid >> 4, bc = (tid & 15) << 2;

    float acc[4][4];
#pragma unroll
    for (int i = 0; i < 4; ++i)
#pragma unroll
        for (int j = 0; j < 4; ++j) acc[i][j] = 0.0f;

    for (int k0 = 0; k0 < K; k0 += 16) {
        float4 av = *(const float4*)(Am + (size_t)(row0 + ar) * K + k0 + ac);
        float4 bv = *(const float4*)(Bm + (size_t)(k0 + bk) * N + col0 + bc);
        As[ac + 0][ar] = av.x; As[ac + 1][ar] = av.y;
        As[ac + 2][ar] = av.z; As[ac + 3][ar] = av.w;
        *(float4*)&Bs[bk][bc] = bv;
        __syncthreads();
#pragma unroll
        for (int kk = 0; kk < 16; ++kk) {
            const float a0 = As[kk][ty * 4 + 0], a1 = As[kk][ty * 4 + 1];
            const float a2 = As[kk][ty * 4 + 2], a3 = As[kk][ty * 4 + 3];
            const float4 b4 = *(const float4*)&Bs[kk][tx * 4];
            acc[0][0] += a0 * b4.x; acc[0][1] += a0 * b4.y; acc[0][2] += a0 * b4.z; acc[0][3] += a0 * b4.w;
            acc[1][0] += a1 * b4.x; acc[1][1] += a1 * b4.y; acc[1][2] += a1 * b4.z; acc[1][3] += a1 * b4.w;
            acc[2][0] += a2 * b4.x; acc[2][1] += a2 * b4.y; acc[2][2] += a2 * b4.z; acc[2][3] += a2 * b4.w;
            acc[3][0] += a3 * b4.x; acc[3][1] += a3 * b4.y; acc[3][2] += a3 * b4.z; acc[3][3] += a3 * b4.w;
        }
        __syncthreads();
    }
#pragma unroll
    for (int i = 0; i < 4; ++i) {
        const int r = row0 + ty * 4 + i;
#pragma unroll
        for (int j = 0; j < 4; ++j) {
            const int c = col0 + tx * 4 + j;
            float v = acc[i][j];
            if (bias) v += bias[c];
            if (act) v = gelu_tanh(v);
            if (resid) v += resid[(size_t)r * N + c];
            Cm[(size_t)r * N + c] = v;
        }
    }
}

// ===================== MFMA scan (round-8 structure, hw sig/tanh) =====================
#define XE_STR 528
#define HB_STR 272

__global__ __launch_bounds__(512, 2) void k_scan_mfma(
    const short* __restrict__ pM, const short* __restrict__ pA, const short* __restrict__ pG,
    const short* __restrict__ pZ, const short* __restrict__ pR, const short* __restrict__ pH,
    const short* __restrict__ pO,
    const float* __restrict__ bz, const float* __restrict__ br, const float* __restrict__ bh,
    const float* __restrict__ us, const float* __restrict__ Hu, const float* __restrict__ u3,
    const float* __restrict__ Kt, float* __restrict__ xs)
{
    __shared__ __align__(16) char XE[16 * XE_STR];
    __shared__ __align__(16) char XT[16 * XE_STR];
    __shared__ __align__(16) char HBs[16 * HB_STR];
    __shared__ __align__(16) char RGs[16 * HB_STR];
    __shared__ __align__(16) char WHH[96 * 1024];

    const int tid = threadIdx.x, w = tid >> 6, l = tid & 63;
    const int m = l & 15, lg = l >> 4;
    const int c0 = 32 * w + 4 * lg;
    const int cg = 16 * w + 4 * lg;

    for (int i = tid; i < (16 * XE_STR) / 4; i += 512) ((int*)XE)[i] = 0;
    for (int i = tid; i < (16 * HB_STR) / 4; i += 512) ((int*)HBs)[i] = 0;
    for (int i = tid; i < 6144; i += 512) ((int4*)WHH)[i] = ((const int4*)pH)[i];

    const f32x4 bzv = *(const f32x4*)(bz + cg);
    const f32x4 brv = *(const f32x4*)(br + cg);
    const f32x4 bhv = *(const f32x4*)(bh + cg);
    f32x4 hFr = {0.f, 0.f, 0.f, 0.f};
    __syncthreads();

    for (int t = 0; t < T0; ++t) {
        const float* usb = us + ((size_t)m * NT + t) * NS;
        const float* hub = Hu + ((size_t)m * NT + t) * NS;
        const float* ktb = Kt + (size_t)t * NS;
        f32x4 us0 = *(const f32x4*)(usb + c0), us1 = *(const f32x4*)(usb + c0 + 16);
        f32x4 hu0 = *(const f32x4*)(hub + c0), hu1 = *(const f32x4*)(hub + c0 + 16);
        f32x4 kv0 = *(const f32x4*)(ktb + c0), kv1 = *(const f32x4*)(ktb + c0 + 16);
        f32x4 p0 = {0.f,0.f,0.f,0.f}, p1 = {0.f,0.f,0.f,0.f};
#pragma unroll
        for (int ks = 0; ks < 8; ++ks) {
            bf16x8 xe = BFRAG(XE, XE_STR, ks);
            p0 = MFMA(GFRAG(pA, (2 * w + 0) * 8 + ks), xe, p0);
            p1 = MFMA(GFRAG(pA, (2 * w + 1) * 8 + ks), xe, p1);
        }
        p0 += us0; p1 += us1;
        st_bf4(XT, XE_STR, m, c0 * 2, p0);
        st_bf4(XT, XE_STR, m, (c0 + 16) * 2, p1);
        SYNCW();
        f32x4 g0 = {0.f,0.f,0.f,0.f}, g1 = {0.f,0.f,0.f,0.f};
#pragma unroll
        for (int ks = 0; ks < 8; ++ks) {
            bf16x8 xt = BFRAG(XT, XE_STR, ks);
            g0 = MFMA(GFRAG(pG, (2 * w + 0) * 8 + ks), xt, g0);
            g1 = MFMA(GFRAG(pG, (2 * w + 1) * 8 + ks), xt, g1);
        }
        f32x4 xq0 = p0 + kv0 * (hu0 - g0);
        f32x4 xq1 = p1 + kv1 * (hu1 - g1);
        st_bf4(XE, XE_STR, m, c0 * 2, xq0);
        st_bf4(XE, XE_STR, m, (c0 + 16) * 2, xq1);
        SYNCW();
        f32x4 za = bzv, ra = brv, hx = bhv;
#pragma unroll
        for (int ks = 0; ks < 4; ++ks) {
            bf16x8 hb = BFRAG(HBs, HB_STR, ks);
            za = MFMA(GFRAG(pZ, w * 12 + ks), hb, za);
            ra = MFMA(GFRAG(pR, w * 12 + ks), hb, ra);
        }
#pragma unroll
        for (int ks = 0; ks < 8; ++ks) {
            bf16x8 xef = BFRAG(XE, XE_STR, ks);
            za = MFMA(GFRAG(pZ, w * 12 + 4 + ks), xef, za);
            ra = MFMA(GFRAG(pR, w * 12 + 4 + ks), xef, ra);
            hx = MFMA(GFRAG(pH, w * 12 + 4 + ks), xef, hx);
        }
        f32x4 z = sig4(za), r = sig4(ra), rg = r * hFr;
        st_bf4(RGs, HB_STR, m, cg * 2, rg);
        SYNCW();
        f32x4 hc = hx;
#pragma unroll
        for (int ks = 0; ks < 4; ++ks)
            hc = MFMA(GFRAG(pH, w * 12 + ks), BFRAG(RGs, HB_STR, ks), hc);
        f32x4 hcv = tanh4(hc);
        f32x4 hn = hFr + z * (hcv - hFr);
        hFr = hn;
        st_bf4(HBs, HB_STR, m, cg * 2, hn);
        SYNCW();
#pragma unroll
        for (int ks = 0; ks < 4; ++ks) {
            bf16x8 hb2 = BFRAG(HBs, HB_STR, ks);
            xq0 = MFMA(GFRAG(pO, (2 * w + 0) * 4 + ks), hb2, xq0);
            xq1 = MFMA(GFRAG(pO, (2 * w + 1) * 4 + ks), hb2, xq1);
        }
        st_bf4(XE, XE_STR, m, c0 * 2, xq0);
        st_bf4(XE, XE_STR, m, (c0 + 16) * 2, xq1);
        {
            float* xb = xs + ((size_t)m * NT + t) * NS;
            *(f32x4*)(xb + c0) = xq0;
            *(f32x4*)(xb + c0 + 16) = xq1;
        }
        SYNCW();
    }

    bf16x8 rM0[8], rM1[8], rZx[8], rRx[8], rZh[4], rRh[4], rO0[4], rO1[4];
#pragma unroll
    for (int ks = 0; ks < 8; ++ks) {
        rM0[ks] = GFRAG(pM, (2 * w + 0) * 8 + ks);
        rM1[ks] = GFRAG(pM, (2 * w + 1) * 8 + ks);
        rZx[ks] = GFRAG(pZ, w * 12 + 4 + ks);
        rRx[ks] = GFRAG(pR, w * 12 + 4 + ks);
    }
#pragma unroll
    for (int ks = 0; ks < 4; ++ks) {
        rZh[ks] = GFRAG(pZ, w * 12 + ks);
        rRh[ks] = GFRAG(pR, w * 12 + ks);
        rO0[ks] = GFRAG(pO, (2 * w + 0) * 4 + ks);
        rO1[ks] = GFRAG(pO, (2 * w + 1) * 4 + ks);
    }

    f32x4 zh = bzv, rh = brv;
#pragma unroll
    for (int ks = 0; ks < 4; ++ks) {
        bf16x8 hb = BFRAG(HBs, HB_STR, ks);
        zh = MFMA(rZh[ks], hb, zh);
        rh = MFMA(rRh[ks], hb, rh);
    }

    for (int t = T0; t < NT; ++t) {
        const float* ubase = u3 + ((size_t)(t * NB) + m) * NS;
        f32x4 cu0 = *(const f32x4*)(ubase + c0);
        f32x4 cu1 = *(const f32x4*)(ubase + c0 + 16);

        f32x4 xq0 = {0.f,0.f,0.f,0.f}, xq1 = {0.f,0.f,0.f,0.f};
#pragma unroll
        for (int ks = 0; ks < 8; ++ks) {
            bf16x8 xe = BFRAG(XE, XE_STR, ks);
            xq0 = MFMA(rM0[ks], xe, xq0);
            xq1 = MFMA(rM1[ks], xe, xq1);
        }
        xq0 += cu0; xq1 += cu1;
        st_bf4(XT, XE_STR, m, c0 * 2, xq0);
        st_bf4(XT, XE_STR, m, (c0 + 16) * 2, xq1);
        SYNCW();  // bar A
        f32x4 za = zh, ra = rh, hx = bhv;
#pragma unroll
        for (int ks = 0; ks < 8; ++ks) {
            bf16x8 xt = BFRAG(XT, XE_STR, ks);
            za = MFMA(rZx[ks], xt, za);
            ra = MFMA(rRx[ks], xt, ra);
            hx = MFMA(LFRAG(WHH, w * 12 + 4 + ks), xt, hx);
        }
        f32x4 z = sig4(za), r = sig4(ra), rg = r * hFr;
        st_bf4(RGs, HB_STR, m, cg * 2, rg);
        SYNCW();  // bar B
        f32x4 hc = hx;
#pragma unroll
        for (int ks = 0; ks < 4; ++ks)
            hc = MFMA(LFRAG(WHH, w * 12 + ks), BFRAG(RGs, HB_STR, ks), hc);
        f32x4 hcv = tanh4(hc);
        f32x4 hn = hFr + z * (hcv - hFr);
        hFr = hn;
        st_bf4(HBs, HB_STR, m, cg * 2, hn);
        SYNCW();  // bar C
        f32x4 zhN = bzv, rhN = brv;
#pragma unroll
        for (int ks = 0; ks < 4; ++ks) {
            bf16x8 hb2 = BFRAG(HBs, HB_STR, ks);
            xq0 = MFMA(rO0[ks], hb2, xq0);
            xq1 = MFMA(rO1[ks], hb2, xq1);
            zhN = MFMA(rZh[ks], hb2, zhN);
            rhN = MFMA(rRh[ks], hb2, rhN);
        }
        st_bf4(XE, XE_STR, m, c0 * 2, xq0);
        st_bf4(XE, XE_STR, m, (c0 + 16) * 2, xq1);
        {
            float* xb = xs + ((size_t)m * NT + t) * NS;
            *(f32x4*)(xb + c0) = xq0;
            *(f32x4*)(xb + c0 + 16) = xq1;
        }
        zh = zhN; rh = rhN;
        SYNCW();  // bar D
    }
}

extern "C" void kernel_launch(void* const* d_in, const int* in_sizes, int n_in,
                              void* d_out, int out_size, void* d_ws, size_t ws_size,
                              hipStream_t stream) {
    (void)in_sizes; (void)n_in; (void)out_size; (void)ws_size;
    const float* x       = (const float*)d_in[0];
    const float* W_in    = (const float*)d_in[1];
    const float* b_in    = (const float*)d_in[2];
    const float* W_state = (const float*)d_in[3];
    const float* b_state = (const float*)d_in[4];
    const float* A       = (const float*)d_in[5];
    const float* H       = (const float*)d_in[6];
    const float* Q       = (const float*)d_in[7];
    const float* R       = (const float*)d_in[8];
    const float* W_z     = (const float*)d_in[9];
    const float* W_r     = (const float*)d_in[10];
    const float* W_h     = (const float*)d_in[11];
    const float* b_z     = (const float*)d_in[12];
    const float* b_r     = (const float*)d_in[13];
    const float* b_h     = (const float*)d_in[14];
    const float* W_out   = (const float*)d_in[15];
    const float* W_outp  = (const float*)d_in[16];
    const float* b_outp  = (const float*)d_in[17];
    float* out = (float*)d_out;
    float* w = (float*)d_ws;

    float* us   = w + OFF_US;
    float* Hu   = w + OFF_HU;
    float* u3   = w + OFF_U3;
    float* Kt   = w + OFF_KT;
    float* Ht   = w + OFF_HT;
    float* At   = w + OFF_AT;
    float* G    = w + OFF_G;
    float* IG   = w + OFF_IG;
    float* Minf = w + OFF_MINF;
    float* Wzt  = w + OFF_WZT;
    float* Wrt  = w + OFF_WRT;
    float* Wht  = w + OFF_WHT;
    float* HtWo = w + OFF_HTWO;
    short* pk   = (short*)(w + OFF_PACK);
    short* xs_pk = (short*)(w + OFF_XSPK);

    short* x_pk  = (short*)out;                       // d_out lower (dead after u-GEMM)
    short* u_pk  = (short*)out;                       // reuses lower after x_pk dead
    short* us_pk = (short*)out;                       // reuses lower after u_pk dead
    float* usG   = out + (size_t)4194304;             // d_out [4.19M..8.39M)
    float* u     = out + (size_t)8388608;             // d_out upper
    float* xs    = out + (size_t)8388608;             // overwrites u

    const int M = NB * NT;  // 16384

    hipLaunchKernelGGL(k_precompute, dim3(1), dim3(512), 0, stream, Q, R, Kt);
    hipLaunchKernelGGL(k_transpose, dim3((NS * NS + 255) / 256), dim3(256), 0, stream, A, At, NS, NS);
    hipLaunchKernelGGL(k_transpose, dim3((ND * NS + 255) / 256), dim3(256), 0, stream, H, Ht, ND, NS);
    hipLaunchKernelGGL(k_transpose, dim3((NH * 384 + 255) / 256), dim3(256), 0, stream, W_z, Wzt, NH, 384);
    hipLaunchKernelGGL(k_transpose, dim3((NH * 384 + 255) / 256), dim3(256), 0, stream, W_r, Wrt, NH, 384);
    hipLaunchKernelGGL(k_transpose, dim3((NH * 384 + 255) / 256), dim3(256), 0, stream, W_h, Wht, NH, 384);
    // exact f32 small GEMMs
    hipLaunchKernelGGL(k_gemm, dim3(NS / 64, NS / 64), dim3(256), 0, stream,
                       Ht, H, nullptr, nullptr, G, NS, NS, ND, 0);           // G = Ht@H
    hipLaunchKernelGGL(k_gemm, dim3(NE / 64, NS / 64), dim3(256), 0, stream,
                       Ht, W_outp, nullptr, nullptr, HtWo, NS, NE, ND, 0);   // HtWo = Ht@W_outp
    hipLaunchKernelGGL(k_ig, dim3(256), dim3(256), 0, stream, G, Kt, IG);
    hipLaunchKernelGGL(k_gemm, dim3(NS / 64, NS / 64), dim3(256), 0, stream,
                       At, IG, nullptr, nullptr, Minf, NS, NS, NS, 0);       // Minf = At@IG
    // weight packs
    hipLaunchKernelGGL(k_pack, dim3((NS * NS + 255) / 256), dim3(256), 0, stream, At, pk + PK_A, NS, NS);
    hipLaunchKernelGGL(k_pack, dim3((NS * NS + 255) / 256), dim3(256), 0, stream, G, pk + PK_G, NS, NS);
    hipLaunchKernelGGL(k_pack, dim3((NS * NS + 255) / 256), dim3(256), 0, stream, Minf, pk + PK_M, NS, NS);
    hipLaunchKernelGGL(k_pack, dim3((384 * NH + 255) / 256), dim3(256), 0, stream, Wzt, pk + PK_Z, 384, NH);
    hipLaunchKernelGGL(k_pack, dim3((384 * NH + 255) / 256), dim3(256), 0, stream, Wrt, pk + PK_R, 384, NH);
    hipLaunchKernelGGL(k_pack, dim3((384 * NH + 255) / 256), dim3(256), 0, stream, Wht, pk + PK_H, 384, NH);
    hipLaunchKernelGGL(k_pack, dim3((NH * NS + 255) / 256), dim3(256), 0, stream, W_out, pk + PK_O, NH, NS);
    hipLaunchKernelGGL(k_pack, dim3((NE * ND + 255) / 256), dim3(256), 0, stream, W_in, pk + PK_WIN, NE, ND);
    hipLaunchKernelGGL(k_pack, dim3((ND * NS + 255) / 256), dim3(256), 0, stream, W_state, pk + PK_WST, ND, NS);
    hipLaunchKernelGGL(k_pack, dim3((ND * NS + 255) / 256), dim3(256), 0, stream, H, pk + PK_HM, ND, NS);
    hipLaunchKernelGGL(k_pack, dim3((NS * NE + 255) / 256), dim3(256), 0, stream, HtWo, pk + PK_HTW, NS, NE);
    // u = gelu(x@W_in + b_in)
    hipLaunchKernelGGL(k_packA, dim3((M * NE) / 256), dim3(256), 0, stream, x, x_pk, NE, M * NE);
    hipLaunchKernelGGL(k_mm, dim3(M / 64, ND / 128), dim3(256), 0, stream,
                       x_pk, pk + PK_WIN, b_in, nullptr, u, ND, NE, 1);
    // us, Hu
    hipLaunchKernelGGL(k_packA, dim3((M * ND) / 256), dim3(256), 0, stream, u, u_pk, ND, M * ND);
    hipLaunchKernelGGL(k_mm, dim3(M / 64, NS / 128), dim3(256), 0, stream,
                       u_pk, pk + PK_WST, b_state, nullptr, us, NS, ND, 0);
    hipLaunchKernelGGL(k_mm, dim3(M / 64, NS / 128), dim3(256), 0, stream,
                       u_pk, pk + PK_HM, nullptr, nullptr, Hu, NS, ND, 0);
    // usG = us@G ; u3
    hipLaunchKernelGGL(k_packA, dim3((M * NS) / 256), dim3(256), 0, stream, us, us_pk, NS, M * NS);
    hipLaunchKernelGGL(k_mm, dim3(M / 64, NS / 128), dim3(256), 0, stream,
                       us_pk, pk + PK_G, nullptr, nullptr, usG, NS, NS, 0);
    hipLaunchKernelGGL(k_fuse, dim3((NT * NB * NS) / 256), dim3(256), 0, stream,
                       us, usG, Hu, Kt, u3);
    // scan
    hipLaunchKernelGGL(k_scan_mfma, dim3(1), dim3(512), 0, stream,
                       pk + PK_M, pk + PK_A, pk + PK_G, pk + PK_Z, pk + PK_R, pk + PK_H,
                       pk + PK_O,
                       b_z, b_r, b_h, us, Hu, u3, Kt, xs);
    // out = xs@(Ht@W_outp) + b_outp + x
    hipLaunchKernelGGL(k_packA, dim3((M * NS) / 256), dim3(256), 0, stream, xs, xs_pk, NS, M * NS);
    hipLaunchKernelGGL(k_mm, dim3(M / 64, NE / 128), dim3(256), 0, stream,
                       xs_pk, pk + PK_HTW, b_outp, x, out, NE, NS, 0);
}